// Round 6
// baseline (30.952 us; speedup 1.0000x reference)
//
#include <hip/hip_runtime.h>

// B=16, N1=16, TOTAL_IN=1024 (two layers of 512 x dim 8), D1=64
// softmax rows sum to 1 =>  S[b,k,l] = sum_i (1 + rowsum_bias[k,i]) * U[b,k,i,l]
// One block per (k, 8-row i-chunk): grid 2048 -> blocks refill CUs so load
// bursts from fresh blocks cover the serial tails of draining ones.
// Thread (g=tid>>5 row, jb=(tid>>4)&1 j-half, lq=tid&15 l-quad):
//   - 4 coalesced W float4 loads (j = jb*4 + j4), issued first
//   - bias row per 32-lane group, ONE batch of 8 float4 (single latency)
//   - FMA: one broadcast ds_read_b128 per b; j-half reduce = shfl_xor(16),
//     row-pair reduce = shfl_xor(32); cross-wave via rbuf (v5 skeleton).

__global__ __launch_bounds__(256) void proj_kernel(
        const float* __restrict__ x0, const float* __restrict__ x1,
        const float* __restrict__ W0, const float* __restrict__ W1,
        const float* __restrict__ bias, float* __restrict__ partial) {
    __shared__ float xs[8 * 132];      // [row][b*8+j], 528B row stride
    __shared__ float ssum[8];          // per-row scale
    __shared__ float rbuf[4 * 8 * 64]; // [wave][bi][l] cross-wave reduction, 8KB
    const int tid = threadIdx.x;
    const int k     = blockIdx.x >> 7;     // [0,16)
    const int chunk = blockIdx.x & 127;    // [0,128)
    const int g  = tid >> 5;               // row in chunk [0,8)
    const int h  = tid & 31;               // lane within row group
    const int jb = (tid >> 4) & 1;         // j-half
    const int lq = tid & 15;               // l-quad
    const int w  = tid >> 6;               // wave [0,4)

    const int layer = chunk >> 6;
    const int i0    = (chunk & 63) * 8;    // i within layer [0,512)
    const int ig0   = chunk * 8;           // global i [0,1024)
    const float* __restrict__ x = layer ? x1 : x0;
    const float* __restrict__ W = layer ? W1 : W0;

    // ---- 1. W loads first: thread owns (row g, j = jb*4+j4, l-quad lq).
    // float4 index of W[k][i0+g][j][lq*4] = (k*512+i0+g)*128 + j*16 + lq
    const float4* Wf4 = (const float4*)W;
    const size_t wbase = (size_t)(k * 512 + i0 + g) * 128 + jb * 64 + lq;
    float4 wv[4];
#pragma unroll
    for (int j4 = 0; j4 < 4; ++j4) wv[j4] = Wf4[wbase + j4 * 16];

    // ---- 2. x load: thread -> (b = tid>>4, rl = (tid>>1)&7, half = tid&1)
    const int xb = tid >> 4, xrl = (tid >> 1) & 7, xh = tid & 1;
    const float4 a = ((const float4*)(x + (size_t)(xb * 512 + i0 + xrl) * 8))[xh];

    // ---- 3. bias rowsum for row ig0+g: 32 lanes, one batch of 8 float4
    {
        const float4* bp = (const float4*)(bias + (size_t)(k * 1024 + ig0 + g) * 1024);
        float4 v[8];
#pragma unroll
        for (int it = 0; it < 8; ++it) v[it] = bp[h + 32 * it];
        float s0 = 0.f, s1 = 0.f, s2 = 0.f, s3 = 0.f;
#pragma unroll
        for (int it = 0; it < 8; it += 4) {
            s0 += v[it].x + v[it].y + v[it].z + v[it].w;
            s1 += v[it + 1].x + v[it + 1].y + v[it + 1].z + v[it + 1].w;
            s2 += v[it + 2].x + v[it + 2].y + v[it + 2].z + v[it + 2].w;
            s3 += v[it + 3].x + v[it + 3].y + v[it + 3].z + v[it + 3].w;
        }
        float s = (s0 + s1) + (s2 + s3);
#pragma unroll
        for (int m = 16; m >= 1; m >>= 1) s += __shfl_xor(s, m);  // within 32-lane group
        if (h == 0) ssum[g] = 1.0f + s;
    }
    __syncthreads();

    // ---- 4. stage xs[rl][b*8 + half*4] = x * scale
    {
        const float s = ssum[xrl];
        *(float4*)&xs[xrl * 132 + xb * 8 + xh * 4] =
            make_float4(a.x * s, a.y * s, a.z * s, a.w * s);
    }
    __syncthreads();

    // ---- 5+6. FMA over b in two halves of 8; shfl-reduce j-half + row pair;
    //           cross-wave reduce via rbuf; store fully-reduced tile.
#pragma unroll
    for (int half = 0; half < 2; ++half) {
        float4 acc[8];
#pragma unroll
        for (int bi = 0; bi < 8; ++bi) acc[bi] = make_float4(0.f, 0.f, 0.f, 0.f);
#pragma unroll
        for (int bi = 0; bi < 8; ++bi) {
            const int b = half * 8 + bi;
            const float4 xv = *(const float4*)&xs[g * 132 + b * 8 + jb * 4]; // broadcast
            acc[bi].x += xv.x * wv[0].x + xv.y * wv[1].x + xv.z * wv[2].x + xv.w * wv[3].x;
            acc[bi].y += xv.x * wv[0].y + xv.y * wv[1].y + xv.z * wv[2].y + xv.w * wv[3].y;
            acc[bi].z += xv.x * wv[0].z + xv.y * wv[1].z + xv.z * wv[2].z + xv.w * wv[3].z;
            acc[bi].w += xv.x * wv[0].w + xv.y * wv[1].w + xv.z * wv[2].w + xv.w * wv[3].w;
        }
        // shfl_xor(16): sum two j-halves; shfl_xor(32): sum the wave's row pair
#pragma unroll
        for (int bi = 0; bi < 8; ++bi) {
            acc[bi].x += __shfl_xor(acc[bi].x, 16); acc[bi].x += __shfl_xor(acc[bi].x, 32);
            acc[bi].y += __shfl_xor(acc[bi].y, 16); acc[bi].y += __shfl_xor(acc[bi].y, 32);
            acc[bi].z += __shfl_xor(acc[bi].z, 16); acc[bi].z += __shfl_xor(acc[bi].z, 32);
            acc[bi].w += __shfl_xor(acc[bi].w, 16); acc[bi].w += __shfl_xor(acc[bi].w, 32);
        }
        if ((tid & 48) == 0) {         // lanes 0-15 of each wave
#pragma unroll
            for (int bi = 0; bi < 8; ++bi)
                *(float4*)&rbuf[(w * 8 + bi) * 64 + lq * 4] = acc[bi];
        }
        __syncthreads();
        // cross-wave sum: thread -> (bi = tid>>5, l = tid&31 and +32)
        {
            const int bi = tid >> 5;
            const int l  = tid & 31;
            float v0 = 0.f, v1 = 0.f;
#pragma unroll
            for (int ww = 0; ww < 4; ++ww) {
                v0 += rbuf[(ww * 8 + bi) * 64 + l];
                v1 += rbuf[(ww * 8 + bi) * 64 + l + 32];
            }
            const int b = half * 8 + bi;
            partial[(size_t)blockIdx.x * 1024 + b * 64 + l]      = v0;
            partial[(size_t)blockIdx.x * 1024 + b * 64 + l + 32] = v1;
        }
        __syncthreads();   // protect rbuf rewrite in next half
    }
}

// ---------------------------------------------------------------------------
// One block per (b,k) row: S[b,k,l] = sum over 128 chunk partials; squash.
__global__ __launch_bounds__(256) void reduce_squash_kernel(
        const float* __restrict__ partial, float* __restrict__ out) {
    __shared__ float red[4][64];
    const int row = blockIdx.x;            // [0,256) = b*16 + k
    const int b = row >> 4, k = row & 15;
    const int w = threadIdx.x >> 6, lane = threadIdx.x & 63;
    float s = 0.f;
#pragma unroll
    for (int cc = 0; cc < 32; ++cc) {
        const int c = w + cc * 4;          // wave-interleaved chunks [0,128)
        s += partial[((size_t)(k * 128 + c)) * 1024 + b * 64 + lane];
    }
    red[w][lane] = s;
    __syncthreads();
    if (w == 0) {
        float v = red[0][lane] + red[1][lane] + red[2][lane] + red[3][lane];
        float sq = v * v;
#pragma unroll
        for (int m = 32; m >= 1; m >>= 1) sq += __shfl_xor(sq, m);
        out[(size_t)row * 64 + lane] = (sq / (1.0f + sq)) * v / (sqrtf(sq) + 1e-5f);
    }
}

// ---------------------------------------------------------------------------
extern "C" void kernel_launch(void* const* d_in, const int* in_sizes, int n_in,
                              void* d_out, int out_size, void* d_ws, size_t ws_size,
                              hipStream_t stream) {
    const float* x0  = (const float*)d_in[0];   // [16,512,8]
    const float* x1  = (const float*)d_in[1];   // [16,512,8]
    const float* W0  = (const float*)d_in[2];   // [16,512,8,64]
    const float* W1  = (const float*)d_in[3];   // [16,512,8,64]
    const float* bia = (const float*)d_in[4];   // [16,1024,1024]
    float* out = (float*)d_out;                 // [16,16,64]

    float* partial = (float*)d_ws;              // 2048*1024 floats = 8.4 MB

    proj_kernel<<<dim3(2048), dim3(256), 0, stream>>>(x0, x1, W0, W1, bia, partial);
    reduce_squash_kernel<<<dim3(256), dim3(256), 0, stream>>>(partial, out);
}

// Round 7
// 30.331 us; speedup vs baseline: 1.0205x; 1.0205x over previous
//
#include <hip/hip_runtime.h>

// B=16, N1=16, TOTAL_IN=1024 (two layers of 512 x dim 8), D1=64
// softmax rows sum to 1 =>  S[b,k,l] = sum_i (1 + rowsum_bias[k,i]) * U[b,k,i,l]
// One block per (k, 16-row i-chunk), grid 1024 (v5 grain).
// v7: post-FMA row scaling removes the bias->stage dependency:
//   - xs staged UNSCALED (only x's return gates the barrier)
//   - raw s_barrier + lgkmcnt(0) (no vmcnt drain) so W + bias loads stay
//     in flight across the barrier and land under the FMA phase
//   - bias rowsum computed between FMA half0 and the scale; scale applied
//     to acc (per-thread row g) BEFORE the cross-row shfl reduction.

__global__ __launch_bounds__(256) void proj_kernel(
        const float* __restrict__ x0, const float* __restrict__ x1,
        const float* __restrict__ W0, const float* __restrict__ W1,
        const float* __restrict__ bias, float* __restrict__ partial) {
    __shared__ float xs[16 * 132];      // [i_local][b*8+j], 528B row stride
    __shared__ float rbuf[4 * 8 * 64];  // [wave][bi][l] cross-wave reduction, 8KB
    const int tid = threadIdx.x;
    const int k     = blockIdx.x >> 6;     // [0,16)
    const int chunk = blockIdx.x & 63;     // [0,64)
    const int g  = tid >> 4;               // i_local [0,16)
    const int q  = tid & 15;               // l-quad  [0,16)
    const int w  = tid >> 6;               // wave    [0,4)
    const int gw = g & 3;                  // g within wave

    const int layer = chunk >> 5;
    const int i0    = (chunk & 31) * 16;   // i within layer
    const int ig0   = chunk * 16;          // global i
    const float* __restrict__ x = layer ? x1 : x0;
    const float* __restrict__ W = layer ? W1 : W0;

    // ---- 1. x loads FIRST (they gate the stage/barrier)
    const float4* xp = (const float4*)(x + (size_t)(g * 512 + i0 + q) * 8);
    float4 a0 = xp[0], a1 = xp[1];

    // ---- 2. W loads: thread (g,q) owns row i0+g, l-quad q, all j.
    // float4 index of W[k][i0+g][j][q*4] = (k*512+i0+g)*128 + j*16 + q
    const float4* Wf4 = (const float4*)W;
    const size_t wbase = (size_t)(k * 512 + i0 + g) * 128 + q;
    float4 wv[8];
#pragma unroll
    for (int j = 0; j < 8; ++j) wv[j] = Wf4[wbase + j * 16];

    // ---- 3. bias batch-1 loads (consumed only after FMA half0)
    const float4* bp = (const float4*)(bias + (size_t)(k * 1024 + ig0 + g) * 1024);
    float4 va[8];
#pragma unroll
    for (int it = 0; it < 8; ++it) va[it] = bp[q + 16 * it];

    // ---- 4. stage xs[il=q][bb=g][j] = x (UNSCALED)
    *(float4*)&xs[q * 132 + g * 8]     = a0;
    *(float4*)&xs[q * 132 + g * 8 + 4] = a1;
    // drain only this lane's ds_write, then raw barrier: W/bias loads stay
    // in flight across the barrier (no vmcnt(0) drain, unlike __syncthreads)
    asm volatile("s_waitcnt lgkmcnt(0)" ::: "memory");
    __builtin_amdgcn_s_barrier();
    __builtin_amdgcn_sched_barrier(0);

    float scale = 0.f;   // set in half 0

#pragma unroll
    for (int half = 0; half < 2; ++half) {
        // ---- 5. FMA over 8 b's for (row g, l-quad q)
        float4 acc[8];
#pragma unroll
        for (int bi = 0; bi < 8; ++bi) acc[bi] = make_float4(0.f, 0.f, 0.f, 0.f);
#pragma unroll
        for (int bi = 0; bi < 8; ++bi) {
            const int b = half * 8 + bi;
            float xr[8];
            *(float4*)&xr[0] = *(const float4*)&xs[g * 132 + b * 8];      // broadcast
            *(float4*)&xr[4] = *(const float4*)&xs[g * 132 + b * 8 + 4];
#pragma unroll
            for (int j = 0; j < 8; ++j) {
                acc[bi].x += xr[j] * wv[j].x;
                acc[bi].y += xr[j] * wv[j].y;
                acc[bi].z += xr[j] * wv[j].z;
                acc[bi].w += xr[j] * wv[j].w;
            }
        }

        if (half == 0) {
            // ---- 6. bias rowsum for row ig0+g (batch1 hidden under FMA0)
            float s0 = 0.f, s1 = 0.f, s2 = 0.f, s3 = 0.f;
#pragma unroll
            for (int it = 0; it < 8; it += 4) {
                s0 += va[it].x + va[it].y + va[it].z + va[it].w;
                s1 += va[it + 1].x + va[it + 1].y + va[it + 1].z + va[it + 1].w;
                s2 += va[it + 2].x + va[it + 2].y + va[it + 2].z + va[it + 2].w;
                s3 += va[it + 3].x + va[it + 3].y + va[it + 3].z + va[it + 3].w;
            }
            float4 vb[8];
#pragma unroll
            for (int it = 0; it < 8; ++it) vb[it] = bp[q + 16 * (8 + it)];
#pragma unroll
            for (int it = 0; it < 8; it += 4) {
                s0 += vb[it].x + vb[it].y + vb[it].z + vb[it].w;
                s1 += vb[it + 1].x + vb[it + 1].y + vb[it + 1].z + vb[it + 1].w;
                s2 += vb[it + 2].x + vb[it + 2].y + vb[it + 2].z + vb[it + 2].w;
                s3 += vb[it + 3].x + vb[it + 3].y + vb[it + 3].z + vb[it + 3].w;
            }
            float s = (s0 + s1) + (s2 + s3);
#pragma unroll
            for (int m = 8; m >= 1; m >>= 1) s += __shfl_xor(s, m);  // 16-lane group
            scale = 1.0f + s;
        }

        // ---- 7. scale this thread's row BEFORE cross-row reduction
#pragma unroll
        for (int bi = 0; bi < 8; ++bi) {
            acc[bi].x *= scale; acc[bi].y *= scale;
            acc[bi].z *= scale; acc[bi].w *= scale;
        }

        // reduce over the 4 g-rows in this wave (lane bits 4,5)
#pragma unroll
        for (int bi = 0; bi < 8; ++bi) {
            acc[bi].x += __shfl_xor(acc[bi].x, 32); acc[bi].x += __shfl_xor(acc[bi].x, 16);
            acc[bi].y += __shfl_xor(acc[bi].y, 32); acc[bi].y += __shfl_xor(acc[bi].y, 16);
            acc[bi].z += __shfl_xor(acc[bi].z, 32); acc[bi].z += __shfl_xor(acc[bi].z, 16);
            acc[bi].w += __shfl_xor(acc[bi].w, 32); acc[bi].w += __shfl_xor(acc[bi].w, 16);
        }
        if (gw == 0) {
            // each wave writes its own disjoint rbuf region
#pragma unroll
            for (int bi = 0; bi < 8; ++bi)
                *(float4*)&rbuf[(w * 8 + bi) * 64 + q * 4] = acc[bi];
        }
        __syncthreads();
        // cross-wave sum: thread -> (bi = tid>>5, l = tid&31 and +32)
        {
            const int bi = tid >> 5;
            const int l  = tid & 31;
            float v0 = 0.f, v1 = 0.f;
#pragma unroll
            for (int ww = 0; ww < 4; ++ww) {
                v0 += rbuf[(ww * 8 + bi) * 64 + l];
                v1 += rbuf[(ww * 8 + bi) * 64 + l + 32];
            }
            const int b = half * 8 + bi;
            partial[(size_t)blockIdx.x * 1024 + b * 64 + l]      = v0;
            partial[(size_t)blockIdx.x * 1024 + b * 64 + l + 32] = v1;
        }
        __syncthreads();   // protect rbuf rewrite in next half
    }
}

// ---------------------------------------------------------------------------
// One block per (b,k) row: S[b,k,l] = sum over 64 chunk partials; squash.
__global__ __launch_bounds__(256) void reduce_squash_kernel(
        const float* __restrict__ partial, float* __restrict__ out) {
    __shared__ float red[4][64];
    const int row = blockIdx.x;            // [0,256) = b*16 + k
    const int b = row >> 4, k = row & 15;
    const int w = threadIdx.x >> 6, lane = threadIdx.x & 63;
    float s = 0.f;
#pragma unroll
    for (int cc = 0; cc < 16; ++cc) {
        const int c = w + cc * 4;          // wave-interleaved chunks [0,64)
        s += partial[((size_t)(k * 64 + c)) * 1024 + b * 64 + lane];
    }
    red[w][lane] = s;
    __syncthreads();
    if (w == 0) {
        float v = red[0][lane] + red[1][lane] + red[2][lane] + red[3][lane];
        float sq = v * v;
#pragma unroll
        for (int m = 32; m >= 1; m >>= 1) sq += __shfl_xor(sq, m);
        out[(size_t)row * 64 + lane] = (sq / (1.0f + sq)) * v / (sqrtf(sq) + 1e-5f);
    }
}

// ---------------------------------------------------------------------------
extern "C" void kernel_launch(void* const* d_in, const int* in_sizes, int n_in,
                              void* d_out, int out_size, void* d_ws, size_t ws_size,
                              hipStream_t stream) {
    const float* x0  = (const float*)d_in[0];   // [16,512,8]
    const float* x1  = (const float*)d_in[1];   // [16,512,8]
    const float* W0  = (const float*)d_in[2];   // [16,512,8,64]
    const float* W1  = (const float*)d_in[3];   // [16,512,8,64]
    const float* bia = (const float*)d_in[4];   // [16,1024,1024]
    float* out = (float*)d_out;                 // [16,16,64]

    float* partial = (float*)d_ws;              // 1024*1024 floats = 4 MB

    proj_kernel<<<dim3(1024), dim3(256), 0, stream>>>(x0, x1, W0, W1, bia, partial);
    reduce_squash_kernel<<<dim3(256), dim3(256), 0, stream>>>(partial, out);
}